// Round 8
// baseline (93.820 us; speedup 1.0000x reference)
//
#include <hip/hip_runtime.h>

// Depthwise 11x11 box blur, reflect pad, fp32, (16,64,256,256).
// Separable, register-resident vertical ring + shuffle horizontal.
// NO LDS data plane, NO barriers.
//
// Round-8: occupancy lever WITHOUT the round-6 spill trap. Round 7 compiled
// to 52 VGPR -> 8 waves/SIMD already fits in HW (512/52 -> 8). So keep
// __launch_bounds__(256,4) (128-VGPR budget, no allocator squeeze; round 6's
// (256,8) demoted the ring to scratch) and simply supply more blocks:
// strip 32, grid 2048 -> 8 blocks/CU = 32 waves/CU resident. Identical code
// to round 7 otherwise (ring, MLP-4 prefetch, shuffles, NT stores).
// Read amp 1.16x -> 1.31x (~+38MB, halos largely L3-hit).

typedef float f32x4 __attribute__((ext_vector_type(4)));

#define PAD   5
#define IMG   256
#define STRIP 32
#define PRE   (2 * PAD)          // 10 priming iterations
#define ITERS (STRIP + PRE)      // 42
#define MLP   4                  // prefetch depth

__device__ __forceinline__ int refl(int r) {
    return (r < 0) ? -r : ((r > IMG - 1) ? 2 * (IMG - 1) - r : r);
}

__global__ __launch_bounds__(256, 4)
void blur_box11_kernel(const float* __restrict__ in,
                       const float* __restrict__ kern,
                       float* __restrict__ out) {
    const int lane = threadIdx.x & 63;
    const int wv   = threadIdx.x >> 6;             // 0..3
    const int img  = blockIdx.x >> 1;              // 0..1023
    const int half = blockIdx.x & 1;               // 0..1
    const int S    = half * 128 + wv * STRIP;      // strip's first output row
    const int X0   = lane * 4;                     // lane's 4 columns

    const float* src = in  + (size_t)img * (IMG * IMG);
    float*       dst = out + (size_t)img * (IMG * IMG);
    const float  kv  = kern[0];                    // 1/121 (uniform box)

#define LOADROW(i) (*reinterpret_cast<const f32x4*>( \
        src + (size_t)refl(S - PAD + (i)) * IMG + X0))

    f32x4 ring[11];
#pragma unroll
    for (int k = 0; k < 11; ++k) ring[k] = (f32x4)0.0f;
    f32x4 cs = (f32x4)0.0f;

    // 4-deep prefetch pipeline: 4 outstanding 1KB loads per wave
    f32x4 q0 = LOADROW(0);
    f32x4 q1 = LOADROW(1);
    f32x4 q2 = LOADROW(2);
    f32x4 q3 = LOADROW(3);

#pragma unroll
    for (int i = 0; i < ITERS; ++i) {              // full unroll: ring idx static
        f32x4 v = q0;
        q0 = q1; q1 = q2; q2 = q3;
        if (i + MLP < ITERS) q3 = LOADROW(i + MLP);

        cs += v - ring[i % 11];                    // vertical sliding 11-sum
        ring[i % 11] = v;

        if (i >= PRE) {
            const int row = S + i - PRE;           // output row S..S+31

            // assemble cols X0-5 .. X0+8 (v0..v13) in registers
            float v0  = __shfl(cs.w, lane - 2);
            float v1  = __shfl(cs.x, lane - 1);
            float v2  = __shfl(cs.y, lane - 1);
            float v3  = __shfl(cs.z, lane - 1);
            float v4  = __shfl(cs.w, lane - 1);
            float v5  = cs.x, v6 = cs.y, v7 = cs.z, v8 = cs.w;
            float v9  = __shfl(cs.x, lane + 1);
            float v10 = __shfl(cs.y, lane + 1);
            float v11 = __shfl(cs.z, lane + 1);
            float v12 = __shfl(cs.w, lane + 1);
            float v13 = __shfl(cs.x, lane + 2);

            // reflect fixups (also repair out-of-range shuffle slots)
            if (lane == 0)       { v0 = v10; v1 = v9; v2 = v8; v3 = v7; v4 = v6; }
            else if (lane == 1)  { v0 = v2; }
            if (lane == 63)      { v9 = v7; v10 = v6; v11 = v5; v12 = v4; v13 = v3; }
            else if (lane == 62) { v13 = v11; }

            // sliding 11-sum over the 14-col window -> 4 outputs
            float s0 = ((v0 + v1) + (v2 + v3)) + ((v4 + v5) + (v6 + v7))
                     + ((v8 + v9) + v10);
            float s1 = s0 - v0 + v11;
            float s2 = s1 - v1 + v12;
            float s3 = s2 - v2 + v13;

            f32x4 o;
            o.x = s0 * kv; o.y = s1 * kv; o.z = s2 * kv; o.w = s3 * kv;
            __builtin_nontemporal_store(
                o, reinterpret_cast<f32x4*>(dst + (size_t)row * IMG + X0));
        }
    }
#undef LOADROW
}

extern "C" void kernel_launch(void* const* d_in, const int* in_sizes, int n_in,
                              void* d_out, int out_size, void* d_ws, size_t ws_size,
                              hipStream_t stream) {
    const float* in   = (const float*)d_in[0];
    const float* kern = (const float*)d_in[1];
    float*       out  = (float*)d_out;

    const int n_images = 16 * 64;                  // B * C
    dim3 grid(n_images * 2);                       // 2048 blocks, 4 waves each
    dim3 block(256);
    blur_box11_kernel<<<grid, block, 0, stream>>>(in, kern, out);
}

// Round 9
// 88.245 us; speedup vs baseline: 1.0632x; 1.0632x over previous
//
#include <hip/hip_runtime.h>

// Depthwise 11x11 box blur, reflect pad, fp32, (16,64,256,256).
// Separable, register-resident vertical ring + shuffle horizontal.
// NO LDS data plane, NO barriers.
//
// Round-9: traffic lever. R7 (MLP 2->4) and R8 (16->32 waves/CU) were both
// null at fixed bytes: effective BW pinned at 4.5 TB/s HBM-side / 6.17 TB/s
// CU-side (= 98% of the 6.29 TB/s copy ceiling). Only lever left: move fewer
// bytes. Strip 64 -> 128 rows/wave cuts vertical halo amp 1.16x -> 1.08x
// (-21 MiB). Wave = full 256-col row; 2048 waves = 512 blocks = 2 blocks/CU.
// Loop restructured as outer x inner-unroll-11 so ring indices stay static
// (i = ib*11 + j  =>  i % 11 == j) without a 138-body icache-busting unroll.
//
// Vertical: 11-deep float4 register ring + MLP-4 explicit prefetch.
// Horizontal: 11-tap via 10 __shfl + edge reflect fixups, sliding-sum ->
//           4 outputs -> one nontemporal float4 store.

typedef float f32x4 __attribute__((ext_vector_type(4)));

#define PAD   5
#define IMG   256
#define STRIP 128
#define PRE   (2 * PAD)          // 10 priming iterations
#define ITERS (STRIP + PRE)      // 138
#define MLP   4                  // prefetch depth

__device__ __forceinline__ int refl(int r) {
    return (r < 0) ? -r : ((r > IMG - 1) ? 2 * (IMG - 1) - r : r);
}

__global__ __launch_bounds__(256, 4)
void blur_box11_kernel(const float* __restrict__ in,
                       const float* __restrict__ kern,
                       float* __restrict__ out) {
    const int lane = threadIdx.x & 63;
    const int wv   = threadIdx.x >> 6;             // 0..3
    const int gw   = blockIdx.x * 4 + wv;          // global wave id, 0..2047
    const int img  = gw >> 1;                      // 0..1023
    const int S    = (gw & 1) * STRIP;             // strip's first output row
    const int X0   = lane * 4;                     // lane's 4 columns

    const float* src = in  + (size_t)img * (IMG * IMG);
    float*       dst = out + (size_t)img * (IMG * IMG);
    const float  kv  = kern[0];                    // 1/121 (uniform box)

#define LOADROW(i) (*reinterpret_cast<const f32x4*>( \
        src + (size_t)refl(S - PAD + (i)) * IMG + X0))

    f32x4 ring[11];
#pragma unroll
    for (int k = 0; k < 11; ++k) ring[k] = (f32x4)0.0f;
    f32x4 cs = (f32x4)0.0f;

    // 4-deep prefetch pipeline: 4 outstanding 1KB loads per wave
    f32x4 q0 = LOADROW(0);
    f32x4 q1 = LOADROW(1);
    f32x4 q2 = LOADROW(2);
    f32x4 q3 = LOADROW(3);

    for (int ib = 0; ib < (ITERS + 10) / 11; ++ib) {
#pragma unroll
        for (int j = 0; j < 11; ++j) {
            const int i = ib * 11 + j;             // i % 11 == j (static ring idx)
            if (i >= ITERS) break;                 // wave-uniform guard

            f32x4 v = q0;
            q0 = q1; q1 = q2; q2 = q3;
            if (i + MLP < ITERS) q3 = LOADROW(i + MLP);

            cs += v - ring[j];                     // vertical sliding 11-sum
            ring[j] = v;

            if (i >= PRE) {
                const int row = S + i - PRE;       // output row S..S+127

                // assemble cols X0-5 .. X0+8 (v0..v13) in registers
                float v0  = __shfl(cs.w, lane - 2);
                float v1  = __shfl(cs.x, lane - 1);
                float v2  = __shfl(cs.y, lane - 1);
                float v3  = __shfl(cs.z, lane - 1);
                float v4  = __shfl(cs.w, lane - 1);
                float v5  = cs.x, v6 = cs.y, v7 = cs.z, v8 = cs.w;
                float v9  = __shfl(cs.x, lane + 1);
                float v10 = __shfl(cs.y, lane + 1);
                float v11 = __shfl(cs.z, lane + 1);
                float v12 = __shfl(cs.w, lane + 1);
                float v13 = __shfl(cs.x, lane + 2);

                // reflect fixups (also repair out-of-range shuffle slots)
                if (lane == 0)       { v0 = v10; v1 = v9; v2 = v8; v3 = v7; v4 = v6; }
                else if (lane == 1)  { v0 = v2; }
                if (lane == 63)      { v9 = v7; v10 = v6; v11 = v5; v12 = v4; v13 = v3; }
                else if (lane == 62) { v13 = v11; }

                // sliding 11-sum over the 14-col window -> 4 outputs
                float s0 = ((v0 + v1) + (v2 + v3)) + ((v4 + v5) + (v6 + v7))
                         + ((v8 + v9) + v10);
                float s1 = s0 - v0 + v11;
                float s2 = s1 - v1 + v12;
                float s3 = s2 - v2 + v13;

                f32x4 o;
                o.x = s0 * kv; o.y = s1 * kv; o.z = s2 * kv; o.w = s3 * kv;
                __builtin_nontemporal_store(
                    o, reinterpret_cast<f32x4*>(dst + (size_t)row * IMG + X0));
            }
        }
    }
#undef LOADROW
}

extern "C" void kernel_launch(void* const* d_in, const int* in_sizes, int n_in,
                              void* d_out, int out_size, void* d_ws, size_t ws_size,
                              hipStream_t stream) {
    const float* in   = (const float*)d_in[0];
    const float* kern = (const float*)d_in[1];
    float*       out  = (float*)d_out;

    const int n_images = 16 * 64;                  // B * C
    dim3 grid(n_images * 2 / 4);                   // 512 blocks, 4 waves each
    dim3 block(256);
    blur_box11_kernel<<<grid, block, 0, stream>>>(in, kern, out);
}